// Round 6
// baseline (5303.098 us; speedup 1.0000x reference)
//
#include <hip/hip_runtime.h>
#include <hip/hip_fp16.h>

#define Hh 256
#define Ww 256
#define HWn (Hh*Ww)
#define Bn 4

enum { ACT_NONE=0, ACT_RELU=1, ACT_LRELU=2 };

__device__ __forceinline__ float act_apply(float v, int mode){
  if (mode==ACT_RELU)  return fmaxf(v,0.f);
  if (mode==ACT_LRELU) return v>0.f? v : 0.1f*v;
  return v;
}

// ---------------------------------------------------------------------------
// flow warp: warped[b,c,y,x] = bilinear_zero(supp[b,c], y+fy, x+fx)
// grid (HW/256, nb); all pointers pre-offset to batch b0 by host.
// ---------------------------------------------------------------------------
__global__ __launch_bounds__(256)
void warp_k(const float* __restrict__ supp, const float* __restrict__ flow,
            float* __restrict__ out)
{
  int pix = blockIdx.x*256 + threadIdx.x;     // [0, HW)
  int b   = blockIdx.y;
  int py = pix >> 8, px = pix & 255;
  float fx = flow[((size_t)b*2+0)*HWn + pix];
  float fy = flow[((size_t)b*2+1)*HWn + pix];
  float sy = (float)py + fy, sx = (float)px + fx;
  float y0f = floorf(sy), x0f = floorf(sx);
  float wy = sy - y0f,   wx = sx - x0f;
  int y0 = (int)y0f, x0 = (int)x0f;
  int vy0 = (y0>=0)&&(y0<Hh), vy1 = (y0+1>=0)&&(y0+1<Hh);
  int vx0 = (x0>=0)&&(x0<Ww), vx1 = (x0+1>=0)&&(x0+1<Ww);
  int yc0 = min(max(y0,0),Hh-1),  yc1 = min(max(y0+1,0),Hh-1);
  int xc0 = min(max(x0,0),Ww-1),  xc1 = min(max(x0+1,0),Ww-1);
  float w00 = (1.f-wy)*(1.f-wx)*(float)(vy0&vx0);
  float w01 = (1.f-wy)*wx      *(float)(vy0&vx1);
  float w10 = wy*(1.f-wx)      *(float)(vy1&vx0);
  float w11 = wy*wx            *(float)(vy1&vx1);
  size_t i00 = (size_t)yc0*Ww+xc0, i01 = (size_t)yc0*Ww+xc1;
  size_t i10 = (size_t)yc1*Ww+xc0, i11 = (size_t)yc1*Ww+xc1;
  const float* sb = supp + (size_t)b*64*HWn;
  #pragma unroll 4
  for (int c=0;c<64;++c){
    const float* p = sb + (size_t)c*HWn;
    float v = w00*p[i00] + w01*p[i01] + w10*p[i10] + w11*p[i11];
    out[((size_t)b*64+c)*HWn + pix] = v;
  }
}

// ---------------------------------------------------------------------------
// direct 3x3 conv, dilation D, pad D. 16x16 pixel tile / block (256 thr).
// Thread = 8 consecutive x-pixels x 8 couts. cin chunked by 8 through LDS.
// CIN==128 reads channels 0..63 from in0, 64..127 from in1 (concat).
// Couts beyond coutTotal are guarded (216-ch offset conv runs as 4x64).
// OUTH: write fp16 to outh instead of f32 to out (offset conv).
// Epilogue: out = (addsrc? addsrc + addscale*act(v) : act(v)); bias included.
// ---------------------------------------------------------------------------
template<int D, int CIN, bool OUTH>
__global__ __launch_bounds__(256,2)
void conv3x3_k(const float* __restrict__ in0, const float* __restrict__ in1,
               const float* __restrict__ wgt, const float* __restrict__ bias,
               const float* __restrict__ addsrc, float addscale,
               float* __restrict__ out, __half* __restrict__ outh,
               int coutTotal, int actMode)
{
  constexpr int COUTB = 64;
  constexpr int ROWS = 16 + 2*D;
  constexpr int WT   = 16 + 2*D;
  constexpr int WS   = (WT + 3) & ~3;      // padded row stride: 20,20,24
  constexpr int TT   = ROWS*WS;
  constexpr int NCHUNK = CIN/8;
  __shared__ float in_t[8*TT];
  __shared__ float w_t[72*COUTB];          // [cin8*9][COUTB]

  const int tid = threadIdx.x;
  const int og  = tid & 7;                 // cout group
  const int pg  = tid >> 3;                // pixel group 0..31
  const int r   = pg >> 1;                 // tile row 0..15
  const int cc  = (pg & 1)*8;              // tile col base 0/8
  const int tileY = (blockIdx.x >> 4)*16, tileX = (blockIdx.x & 15)*16;
  const int b = blockIdx.y;
  const int coutBase = blockIdx.z*COUTB;

  float acc[8][8];
  {
    float bv[8];
    #pragma unroll
    for (int o=0;o<8;++o){
      int co = coutBase + og*8 + o;
      bv[o] = (co < coutTotal) ? bias[co] : 0.f;
    }
    #pragma unroll
    for (int j=0;j<8;++j)
      #pragma unroll
      for (int o=0;o<8;++o) acc[j][o] = bv[o];
  }

  for (int chk=0; chk<NCHUNK; ++chk){
    __syncthreads();
    const int cinBase = chk*8;
    // ---- stage input tile (zero-padded halo) ----
    for (int idx=tid; idx < 8*ROWS*WT; idx += 256){
      int c   = idx / (ROWS*WT);
      int rem = idx - c*(ROWS*WT);
      int rr  = rem / WT;
      int xx  = rem - rr*WT;
      int gy = tileY - D + rr, gx = tileX - D + xx;
      int cg = cinBase + c;
      float v = 0.f;
      if (gy>=0 && gy<Hh && gx>=0 && gx<Ww){
        const float* src; int cl;
        if (CIN==128){ if (cg<64){ src=in0; cl=cg; } else { src=in1; cl=cg-64; } }
        else         { src=in0; cl=cg; }
        v = src[((size_t)b*64 + cl)*HWn + (size_t)gy*Ww + gx];
      }
      in_t[c*TT + rr*WS + xx] = v;
    }
    // ---- stage weights: w_t[(c*9+tap)*COUTB + oo] ----
    for (int idx=tid; idx < 72*COUTB; idx += 256){
      int oo = idx / 72;
      int rr = idx - oo*72;                // = c*9 + tap, contiguous in global
      float wv = 0.f;
      if (coutBase + oo < coutTotal)
        wv = wgt[((size_t)(coutBase+oo)*CIN + cinBase)*9 + rr];
      w_t[rr*COUTB + oo] = wv;
    }
    __syncthreads();
    // ---- compute ----
    #pragma unroll
    for (int c=0;c<8;++c){
      #pragma unroll
      for (int ki=0;ki<3;++ki){
        constexpr int NR = (D==4)?16:12;
        float row[NR];
        const float4* rb = (const float4*)&in_t[c*TT + (r + ki*D)*WS + cc];
        #pragma unroll
        for (int q=0;q<NR/4;++q){
          float4 t = rb[q];
          row[4*q+0]=t.x; row[4*q+1]=t.y; row[4*q+2]=t.z; row[4*q+3]=t.w;
        }
        #pragma unroll
        for (int kj=0;kj<3;++kj){
          const float4* wb = (const float4*)&w_t[(c*9 + ki*3 + kj)*COUTB + og*8];
          float4 w0 = wb[0], w1 = wb[1];
          float wv[8] = {w0.x,w0.y,w0.z,w0.w,w1.x,w1.y,w1.z,w1.w};
          #pragma unroll
          for (int o=0;o<8;++o)
            #pragma unroll
            for (int j=0;j<8;++j)
              acc[j][o] = fmaf(row[kj*D + j], wv[o], acc[j][o]);
        }
      }
    }
  }
  // ---- epilogue ----
  #pragma unroll
  for (int o=0;o<8;++o){
    int co = coutBase + og*8 + o;
    if (co >= coutTotal) continue;
    size_t base = ((size_t)(b*coutTotal + co))*HWn
                + (size_t)(tileY + r)*Ww + tileX + cc;
    float v[8];
    #pragma unroll
    for (int j=0;j<8;++j) v[j] = act_apply(acc[j][o], actMode);
    if (addsrc){
      #pragma unroll
      for (int j=0;j<8;++j) v[j] = addsrc[base+j] + addscale*v[j];
    }
    if (!OUTH){
      float4 s0 = {v[0],v[1],v[2],v[3]}, s1 = {v[4],v[5],v[6],v[7]};
      *(float4*)(out+base)   = s0;
      *(float4*)(out+base+4) = s1;
    } else {
      union { __half h[8]; float4 f4; } u;
      #pragma unroll
      for (int j=0;j<8;++j) u.h[j] = __float2half(v[j]);
      *(float4*)(outh+base) = u.f4;
    }
  }
}

// ---------------------------------------------------------------------------
// modulated deformable conv. Block = 16x16 pixel tile, 64 couts.
// Loop taps k (stage 64x64 per-tap weights in LDS), then deform groups dg:
//   every thread samples its own pixel's 8 group-channels (mask applied) into
//   LDS, then the 8pix x 8cout register tile accumulates the 8-ch matmul.
// Offsets/mask computed inline from the raw 216-ch conv output (fp16).
// Channel map (verified vs reference): dy ch = dg*18+2k, dx ch = dg*18+2k+1,
// mask ch = 144+dg*9+k; flow add = fx if channel<72 (i.e. dg<4) else fy.
// ---------------------------------------------------------------------------
__global__ __launch_bounds__(256,2)
void dcn_k(const float* __restrict__ supp, const float* __restrict__ flow,
           const __half* __restrict__ o216, const float* __restrict__ dcnw,
           const float* __restrict__ dcnb, float* __restrict__ out)
{
  __shared__ float w_k[64*64];    // [cin][cout] for current tap
  __shared__ float s_g[8*256];    // [group-chan][pixel]

  const int tid = threadIdx.x;
  const int og  = tid & 7, pg = tid >> 3;
  const int r   = pg >> 1, cc = (pg & 1)*8;
  const int tileY = (blockIdx.x >> 4)*16, tileX = (blockIdx.x & 15)*16;
  const int b = blockIdx.y;

  // sampling pixel owned by this thread
  const int sp = tid;
  const int py = tileY + (sp >> 4), px = tileX + (sp & 15);
  const size_t pixoff = (size_t)py*Ww + px;
  const float fx = flow[((size_t)b*2+0)*HWn + pixoff];
  const float fy = flow[((size_t)b*2+1)*HWn + pixoff];

  float acc[8][8];
  {
    float bv[8];
    #pragma unroll
    for (int o=0;o<8;++o) bv[o] = dcnb[og*8+o];
    #pragma unroll
    for (int j=0;j<8;++j)
      #pragma unroll
      for (int o=0;o<8;++o) acc[j][o] = bv[o];
  }

  for (int k=0;k<9;++k){
    __syncthreads();                       // prev-tap w_k reads done
    for (int idx=tid; idx<4096; idx+=256){ // w_k[c*64+o]
      int c = idx >> 6, o = idx & 63;
      w_k[idx] = dcnw[((size_t)o*64 + c)*9 + k];
    }
    const int ki = k/3 - 1, kj = k%3 - 1;
    for (int dg=0; dg<8; ++dg){
      __syncthreads();                     // w_k staged / prev s_g reads done
      // ---- sampling phase ----
      int chy = dg*18 + 2*k, chx = chy+1, chm = 144 + dg*9 + k;
      float oy = __half2float(o216[((size_t)b*216 + chy)*HWn + pixoff]);
      float ox = __half2float(o216[((size_t)b*216 + chx)*HWn + pixoff]);
      float om = __half2float(o216[((size_t)b*216 + chm)*HWn + pixoff]);
      float fadd = (dg < 4) ? fx : fy;     // dy/dx channels both <72 iff dg<4
      float dy = 25.f*tanhf(oy) + fadd;
      float dx = 25.f*tanhf(ox) + fadd;
      float m  = 1.f/(1.f + __expf(-om));
      float sy = (float)py + (float)ki + dy;
      float sx = (float)px + (float)kj + dx;
      float y0f = floorf(sy), x0f = floorf(sx);
      float wy = sy - y0f,   wx = sx - x0f;
      int y0 = (int)y0f, x0 = (int)x0f;
      int vy0 = (y0>=0)&&(y0<Hh), vy1 = (y0+1>=0)&&(y0+1<Hh);
      int vx0 = (x0>=0)&&(x0<Ww), vx1 = (x0+1>=0)&&(x0+1<Ww);
      int yc0 = min(max(y0,0),Hh-1),  yc1 = min(max(y0+1,0),Hh-1);
      int xc0 = min(max(x0,0),Ww-1),  xc1 = min(max(x0+1,0),Ww-1);
      float w00 = (1.f-wy)*(1.f-wx)*(float)(vy0&vx0);
      float w01 = (1.f-wy)*wx      *(float)(vy0&vx1);
      float w10 = wy*(1.f-wx)      *(float)(vy1&vx0);
      float w11 = wy*wx            *(float)(vy1&vx1);
      size_t i00 = (size_t)yc0*Ww+xc0, i01 = (size_t)yc0*Ww+xc1;
      size_t i10 = (size_t)yc1*Ww+xc0, i11 = (size_t)yc1*Ww+xc1;
      const float* sgb = supp + ((size_t)b*64 + dg*8)*HWn;
      #pragma unroll
      for (int cg=0;cg<8;++cg){
        const float* p = sgb + (size_t)cg*HWn;
        float v = w00*p[i00] + w01*p[i01] + w10*p[i10] + w11*p[i11];
        s_g[cg*256 + sp] = v * m;
      }
      __syncthreads();
      // ---- matmul phase ----
      #pragma unroll
      for (int cg=0;cg<8;++cg){
        const float4* ab = (const float4*)&s_g[cg*256 + r*16 + cc];
        float4 a0 = ab[0], a1 = ab[1];
        float av[8] = {a0.x,a0.y,a0.z,a0.w,a1.x,a1.y,a1.z,a1.w};
        const float4* wb = (const float4*)&w_k[(dg*8+cg)*64 + og*8];
        float4 w0 = wb[0], w1 = wb[1];
        float wv[8] = {w0.x,w0.y,w0.z,w0.w,w1.x,w1.y,w1.z,w1.w};
        #pragma unroll
        for (int o=0;o<8;++o)
          #pragma unroll
          for (int j=0;j<8;++j)
            acc[j][o] = fmaf(av[j], wv[o], acc[j][o]);
      }
    }
  }
  // ---- write out ----
  #pragma unroll
  for (int o=0;o<8;++o){
    size_t base = ((size_t)(b*64 + og*8 + o))*HWn + (size_t)(tileY + r)*Ww + tileX + cc;
    float4 s0 = {acc[0][o],acc[1][o],acc[2][o],acc[3][o]};
    float4 s1 = {acc[4][o],acc[5][o],acc[6][o],acc[7][o]};
    *(float4*)(out+base)   = s0;
    *(float4*)(out+base+4) = s1;
  }
}

extern "C" void kernel_launch(void* const* d_in, const int* in_sizes, int n_in,
                              void* d_out, int out_size, void* d_ws, size_t ws_size,
                              hipStream_t stream)
{
  const float* ref  = (const float*)d_in[0];
  const float* supp = (const float*)d_in[1];
  const float* flow = (const float*)d_in[2];
  const float* fc_w = (const float*)d_in[3];
  const float* fc_b = (const float*)d_in[4];
  const float* c1_w = (const float*)d_in[5];
  const float* c1_b = (const float*)d_in[6];
  const float* c2_w = (const float*)d_in[7];
  const float* c2_b = (const float*)d_in[8];
  const float* c3_w = (const float*)d_in[9];
  const float* c3_b = (const float*)d_in[10];
  const float* c4_w = (const float*)d_in[11];
  const float* c4_b = (const float*)d_in[12];
  const float* c5_w = (const float*)d_in[13];
  const float* c5_b = (const float*)d_in[14];
  const float* c6_w = (const float*)d_in[15];
  const float* c6_b = (const float*)d_in[16];
  const float* off_w= (const float*)d_in[17];
  const float* off_b= (const float*)d_in[18];
  const float* dcn_w= (const float*)d_in[19];
  const float* dcn_b= (const float*)d_in[20];

  // Adaptive batch-chunking: process nb batches per chain; ws needs nb*32MB.
  //   ws A [0,        nb*4M floats): warpb (dead after fc) -> t1
  //   ws B [nb*4M,    nb*8M floats): feat0 (dead after c5)
  //   o216h (fp16, nb*27MB)        : ws bytes [0, nb*28311552) overlays A
  //                                  and the dead prefix of B.
  //   accb = d_out + b0*4M floats  : c2/c4/c6 accumulate, offset-conv input,
  //                                  dead before dcn_k overwrites d_out.
  // ws_size is constant across calls -> same branch every call (capture-safe).
  int nb = (ws_size >= (size_t)Bn*33554432) ? Bn
         : (ws_size >= (size_t)2*33554432) ? 2 : 1;

  float* ws = (float*)d_ws;
  for (int b0 = 0; b0 < Bn; b0 += nb){
    const float* refb  = ref  + (size_t)b0*64*HWn;
    const float* suppb = supp + (size_t)b0*64*HWn;
    const float* flowb = flow + (size_t)b0*2*HWn;
    float*  outb  = (float*)d_out + (size_t)b0*64*HWn;
    float*  warpb = ws;                               // A
    float*  t1    = ws;                               // A (after fc)
    float*  feat0 = ws + (size_t)nb*4194304;          // B
    __half* o216h = (__half*)d_ws;                    // overlays A+B prefix
    float*  accb  = outb;

    dim3 cgrid(256, nb, 1);
    warp_k<<<dim3(256,nb),256,0,stream>>>(suppb, flowb, warpb);
    conv3x3_k<1,128,false><<<cgrid,256,0,stream>>>(warpb, refb,    fc_w, fc_b, nullptr, 0.f,  feat0, nullptr, 64, ACT_LRELU);
    conv3x3_k<1, 64,false><<<cgrid,256,0,stream>>>(feat0, nullptr, c1_w, c1_b, nullptr, 0.f,  t1,    nullptr, 64, ACT_RELU);
    conv3x3_k<1, 64,false><<<cgrid,256,0,stream>>>(t1,    nullptr, c2_w, c2_b, feat0,  1.0f,  accb,  nullptr, 64, ACT_RELU);
    conv3x3_k<2, 64,false><<<cgrid,256,0,stream>>>(feat0, nullptr, c3_w, c3_b, nullptr, 0.f,  t1,    nullptr, 64, ACT_RELU);
    conv3x3_k<2, 64,false><<<cgrid,256,0,stream>>>(t1,    nullptr, c4_w, c4_b, accb,   0.1f,  accb,  nullptr, 64, ACT_RELU);
    conv3x3_k<2, 64,false><<<cgrid,256,0,stream>>>(feat0, nullptr, c5_w, c5_b, nullptr, 0.f,  t1,    nullptr, 64, ACT_RELU);
    conv3x3_k<4, 64,false><<<cgrid,256,0,stream>>>(t1,    nullptr, c6_w, c6_b, accb,   0.1f,  accb,  nullptr, 64, ACT_RELU);
    conv3x3_k<1, 64,true ><<<dim3(256,nb,4),256,0,stream>>>(accb, nullptr, off_w, off_b, nullptr, 0.f, nullptr, o216h, 216, ACT_NONE);
    dcn_k<<<dim3(256,nb),256,0,stream>>>(suppb, flowb, o216h, dcn_w, dcn_b, outb);
  }
}

// Round 7
// 3607.636 us; speedup vs baseline: 1.4700x; 1.4700x over previous
//
#include <hip/hip_runtime.h>
#include <hip/hip_fp16.h>

#define Hh 256
#define Ww 256
#define HWn (Hh*Ww)
#define Bn 4

typedef unsigned short u16;
typedef unsigned int   u32;
using bf16x8 = __attribute__((ext_vector_type(8))) short;
using f32x4  = __attribute__((ext_vector_type(4))) float;

enum { ACT_NONE=0, ACT_RELU=1, ACT_LRELU=2 };

__device__ __forceinline__ float act_apply(float v, int mode){
  if (mode==ACT_RELU)  return fmaxf(v,0.f);
  if (mode==ACT_LRELU) return v>0.f? v : 0.1f*v;
  return v;
}
__device__ __forceinline__ u16 f2bf(float x){
  u32 u = __float_as_uint(x);
  u += 0x7FFFu + ((u>>16)&1u);
  return (u16)(u>>16);
}
__device__ __forceinline__ float bf2f(u16 h){
  return __uint_as_float(((u32)h)<<16);
}
__device__ __forceinline__ u32 pck(u16 a, u16 b){ return (u32)a | ((u32)b<<16); }

// write 8 channels (hi at op+cb*16, lo at op+128+cb*16) of a 256B px record
__device__ __forceinline__ void store_hilo8(char* op, int cb, const float* v){
  u16 hs[8], ls[8];
  #pragma unroll
  for (int cc=0; cc<8; ++cc){
    hs[cc] = f2bf(v[cc]);
    ls[cc] = f2bf(v[cc] - bf2f(hs[cc]));
  }
  uint4 ho, lo4;
  ho.x=pck(hs[0],hs[1]); ho.y=pck(hs[2],hs[3]); ho.z=pck(hs[4],hs[5]); ho.w=pck(hs[6],hs[7]);
  lo4.x=pck(ls[0],ls[1]); lo4.y=pck(ls[2],ls[3]); lo4.z=pck(ls[4],ls[5]); lo4.w=pck(ls[6],ls[7]);
  *(uint4*)(op + cb*16)       = ho;
  *(uint4*)(op + 128 + cb*16) = lo4;
}

// ===========================================================================
// MFMA PATH
// Activation tensor layout ("hilo-NHWC"): per px a 256B record =
//   [64 x bf16 hi][64 x bf16 lo]. Tensor = nb batches x 65536 px contiguous.
// Split-GEMM: K' = 3*CIN slot-planes: s0: whi*ahi, s1: whi*alo, s2: wlo*ahi
//  -> error ~2^-17 (f32-grade). kc = 32-k' chunks.
// ===========================================================================

// ---- weight prep: OIHW f32 -> [tap][kc][mt][lane64][e8] bf16 (A-fragments)
__global__ __launch_bounds__(256)
void wprep_k(const float* __restrict__ w, u16* __restrict__ dst,
             int CIN, int NKC, int MT, int coutTotal)
{
  int i = blockIdx.x*256 + threadIdx.x;
  int total = 9*NKC*MT*512;
  if (i >= total) return;
  int e    = i & 7;
  int lane = (i>>3) & 63;
  int rest = i >> 9;
  int mt   = rest % MT;  rest /= MT;
  int kc   = rest % NKC; rest /= NKC;
  int tap  = rest;
  int kp   = kc*32 + (lane>>4)*8 + e;      // k' in [0, NKC*32)
  int s    = kp / CIN;                     // slot 0,1,2
  int c    = kp % CIN;
  int o    = mt*16 + (lane&15);
  float v = 0.f;
  if (o < coutTotal){
    float wv = w[((size_t)o*CIN + c)*9 + tap];
    if (s == 2) v = wv - bf2f(f2bf(wv));   // lo part
    else        v = wv;                    // f2bf below gives hi part
  }
  dst[i] = f2bf(v);
}

// ---- fused flow-warp + hilo-NHWC conversion (one row per block)
__global__ __launch_bounds__(256)
void warpcvt_k(const float* __restrict__ supp, const float* __restrict__ flow,
               u16* __restrict__ dst)
{
  int t = threadIdx.x, y = blockIdx.x, b = blockIdx.y;
  float fx = flow[((size_t)b*2+0)*HWn + (size_t)y*Ww + t];
  float fy = flow[((size_t)b*2+1)*HWn + (size_t)y*Ww + t];
  float sy = (float)y + fy, sx = (float)t + fx;
  float y0f = floorf(sy), x0f = floorf(sx);
  float wy = sy - y0f, wx = sx - x0f;
  int y0 = (int)y0f, x0 = (int)x0f;
  int vy0 = (y0>=0)&&(y0<Hh), vy1 = (y0+1>=0)&&(y0+1<Hh);
  int vx0 = (x0>=0)&&(x0<Ww), vx1 = (x0+1>=0)&&(x0+1<Ww);
  int yc0 = min(max(y0,0),Hh-1),  yc1 = min(max(y0+1,0),Hh-1);
  int xc0 = min(max(x0,0),Ww-1),  xc1 = min(max(x0+1,0),Ww-1);
  float w00 = (1.f-wy)*(1.f-wx)*(float)(vy0&vx0);
  float w01 = (1.f-wy)*wx      *(float)(vy0&vx1);
  float w10 = wy*(1.f-wx)      *(float)(vy1&vx0);
  float w11 = wy*wx            *(float)(vy1&vx1);
  size_t i00 = (size_t)yc0*Ww+xc0, i01 = (size_t)yc0*Ww+xc1;
  size_t i10 = (size_t)yc1*Ww+xc0, i11 = (size_t)yc1*Ww+xc1;
  const float* sb = supp + (size_t)b*64*HWn;
  char* op = (char*)dst + ((size_t)b*HWn + (size_t)y*Ww + t)*256;
  #pragma unroll 1
  for (int cb=0; cb<8; ++cb){
    float v[8];
    #pragma unroll
    for (int cc=0; cc<8; ++cc){
      const float* p = sb + (size_t)(cb*8+cc)*HWn;
      v[cc] = w00*p[i00] + w01*p[i01] + w10*p[i10] + w11*p[i11];
    }
    store_hilo8(op, cb, v);
  }
}

// ---- NCHW f32 -> hilo-NHWC (for ref)
__global__ __launch_bounds__(256)
void refcvt_k(const float* __restrict__ src, u16* __restrict__ dst)
{
  int t = threadIdx.x, y = blockIdx.x, b = blockIdx.y;
  const float* sp = src + (size_t)b*64*HWn + (size_t)y*Ww + t;
  char* op = (char*)dst + ((size_t)b*HWn + (size_t)y*Ww + t)*256;
  #pragma unroll 1
  for (int cb=0; cb<8; ++cb){
    float v[8];
    #pragma unroll
    for (int cc=0; cc<8; ++cc) v[cc] = sp[(size_t)(cb*8+cc)*HWn];
    store_hilo8(op, cb, v);
  }
}

// ---- MFMA implicit-GEMM 3x3 conv (dilation D, pad D), one y-row per block.
// Block: 256 thr = 4 waves; wave w computes all 64 couts x 64 px (w*64..).
// B staged in LDS per kc: 3 rows (y0-D,y0,y0+D) x (256+2D) px x 32k' bf16,
// px-stride 80B (64B data + 16B pad -> 2-way bank = free).
// A-fragments read directly from wprep global (L2-broadcast).
// EPI: 0 = hilo-NHWC out (+bias, act, optional addsrc residual)
//      2 = fp16 NCHW out (offset conv; grid.z=4 cout-blocks, guard 216)
template<int D, int NKC, bool FC, int EPI>
__global__ __launch_bounds__(256,2)
void mconv_k(const u16* __restrict__ in0, const u16* __restrict__ in1,
             const u16* __restrict__ wp, int MTt,
             const float* __restrict__ bias,
             const u16* __restrict__ addsrc, float addscale,
             u16* __restrict__ outT, __half* __restrict__ outH,
             int coutTotal, int actMode)
{
  constexpr int PXR = 256 + 2*D;
  constexpr int RSTRIDE = 80;
  constexpr int ROWB = PXR*RSTRIDE;
  constexpr int NCH = 3*PXR*4;
  __shared__ __align__(16) char lds[69632];

  const int tid  = threadIdx.x;
  const int lane = tid & 63;
  const int wavePx = (tid >> 6) * 64;
  const int y0 = blockIdx.x;
  const int b  = blockIdx.y;
  const int zb = blockIdx.z;

  const char* sA = (const char*)in0 + (size_t)b*HWn*256;
  const char* sB = FC ? ((const char*)in1 + (size_t)b*HWn*256) : nullptr;

  f32x4 zz = {0.f,0.f,0.f,0.f};
  f32x4 acc[4][4];
  #pragma unroll
  for (int m=0;m<4;++m)
    #pragma unroll
    for (int n=0;n<4;++n) acc[m][n] = zz;

  #pragma unroll 1
  for (int kc=0; kc<NKC; ++kc){
    __syncthreads();
    const char* src; int off;
    if (!FC){
      int s = kc>>1; src = sA; off = ((s==1)?128:0) + (kc&1)*64;
    } else {
      int s = kc>>2; int hf = kc&3;
      src = (hf<2) ? sA : sB;
      off = ((s==1)?128:0) + (hf&1)*64;
    }
    for (int idx=tid; idx<NCH; idx+=256){
      int ri = idx/(PXR*4); int rem = idx - ri*(PXR*4);
      int px = rem>>2, ch = rem&3;
      int yy = y0 + (ri-1)*D, gx = px - D;
      uint4 val = {0u,0u,0u,0u};
      if (yy>=0 && yy<Hh && gx>=0 && gx<Ww)
        val = *(const uint4*)(src + (size_t)(yy*Ww + gx)*256 + off + ch*16);
      *(uint4*)(lds + ri*ROWB + px*RSTRIDE + ch*16) = val;
    }
    __syncthreads();
    #pragma unroll 1
    for (int tap=0; tap<9; ++tap){
      int dyi = tap/3, dxi = tap%3;
      const bf16x8* ab = (const bf16x8*)wp
                       + ((size_t)(tap*NKC + kc)*MTt + zb*4)*64 + lane;
      bf16x8 af[4];
      #pragma unroll
      for (int m=0;m<4;++m) af[m] = ab[m*64];
      bf16x8 bfv[4];
      #pragma unroll
      for (int n=0;n<4;++n){
        int slot = wavePx + n*16 + (lane&15) + dxi*D;
        bfv[n] = *(const bf16x8*)(lds + dyi*ROWB + slot*RSTRIDE + (lane>>4)*16);
      }
      #pragma unroll
      for (int m=0;m<4;++m)
        #pragma unroll
        for (int n=0;n<4;++n)
          acc[m][n] = __builtin_amdgcn_mfma_f32_16x16x32_bf16(af[m], bfv[n], acc[m][n], 0,0,0);
    }
  }
  // ---- epilogue: transpose via LDS ([px][c], stride 68 f32) ----
  __syncthreads();
  float* eld = (float*)lds;
  #pragma unroll
  for (int m=0;m<4;++m)
    #pragma unroll
    for (int n=0;n<4;++n)
      #pragma unroll
      for (int r=0;r<4;++r){
        int px = wavePx + n*16 + (lane&15);
        int c  = m*16 + (lane>>4)*4 + r;
        eld[px*68 + c] = acc[m][n][r];
      }
  __syncthreads();
  const size_t rb = (size_t)b*HWn + (size_t)y0*Ww + tid;
  if (EPI == 2){
    #pragma unroll 1
    for (int c=0; c<64; ++c){
      int co = zb*64 + c;
      if (co < coutTotal){
        float v = eld[tid*68 + c] + bias[co];
        outH[((size_t)b*216 + co)*HWn + (size_t)y0*Ww + tid] = __float2half(v);
      }
    }
  } else {
    const char* asp = addsrc ? ((const char*)addsrc + rb*256) : nullptr;
    char* op = (char*)outT + rb*256;
    #pragma unroll 1
    for (int cb=0; cb<8; ++cb){
      float v[8];
      #pragma unroll
      for (int cc=0; cc<8; ++cc){
        int c = cb*8+cc;
        float x = eld[tid*68 + c] + bias[c];
        v[cc] = act_apply(x, actMode);
      }
      if (asp){
        uint4 ah = *(const uint4*)(asp + cb*16);
        uint4 al = *(const uint4*)(asp + 128 + cb*16);
        u32 hu[4] = {ah.x,ah.y,ah.z,ah.w};
        u32 lu[4] = {al.x,al.y,al.z,al.w};
        #pragma unroll
        for (int cc=0; cc<8; ++cc){
          u16 h = (u16)(hu[cc>>1] >> ((cc&1)*16));
          u16 l = (u16)(lu[cc>>1] >> ((cc&1)*16));
          v[cc] = (bf2f(h) + bf2f(l)) + addscale*v[cc];
        }
      }
      store_hilo8(op, cb, v);
    }
  }
}

// ===========================================================================
// shared: modulated deformable conv (f32 VALU; o216 fp16 NCHW input)
// ===========================================================================
__global__ __launch_bounds__(256,2)
void dcn_k(const float* __restrict__ supp, const float* __restrict__ flow,
           const __half* __restrict__ o216, const float* __restrict__ dcnw,
           const float* __restrict__ dcnb, float* __restrict__ out)
{
  __shared__ float w_k[64*64];
  __shared__ float s_g[8*256];

  const int tid = threadIdx.x;
  const int og  = tid & 7, pg = tid >> 3;
  const int r   = pg >> 1, cc = (pg & 1)*8;
  const int tileY = (blockIdx.x >> 4)*16, tileX = (blockIdx.x & 15)*16;
  const int b = blockIdx.y;

  const int sp = tid;
  const int py = tileY + (sp >> 4), px = tileX + (sp & 15);
  const size_t pixoff = (size_t)py*Ww + px;
  const float fx = flow[((size_t)b*2+0)*HWn + pixoff];
  const float fy = flow[((size_t)b*2+1)*HWn + pixoff];

  float acc[8][8];
  {
    float bv[8];
    #pragma unroll
    for (int o=0;o<8;++o) bv[o] = dcnb[og*8+o];
    #pragma unroll
    for (int j=0;j<8;++j)
      #pragma unroll
      for (int o=0;o<8;++o) acc[j][o] = bv[o];
  }

  for (int k=0;k<9;++k){
    __syncthreads();
    for (int idx=tid; idx<4096; idx+=256){
      int c = idx >> 6, o = idx & 63;
      w_k[idx] = dcnw[((size_t)o*64 + c)*9 + k];
    }
    const int ki = k/3 - 1, kj = k%3 - 1;
    for (int dg=0; dg<8; ++dg){
      __syncthreads();
      int chy = dg*18 + 2*k, chx = chy+1, chm = 144 + dg*9 + k;
      float oy = __half2float(o216[((size_t)b*216 + chy)*HWn + pixoff]);
      float ox = __half2float(o216[((size_t)b*216 + chx)*HWn + pixoff]);
      float om = __half2float(o216[((size_t)b*216 + chm)*HWn + pixoff]);
      float fadd = (dg < 4) ? fx : fy;
      float dy = 25.f*tanhf(oy) + fadd;
      float dx = 25.f*tanhf(ox) + fadd;
      float m  = 1.f/(1.f + __expf(-om));
      float sy = (float)py + (float)ki + dy;
      float sx = (float)px + (float)kj + dx;
      float y0f = floorf(sy), x0f = floorf(sx);
      float wy = sy - y0f,   wx = sx - x0f;
      int y0 = (int)y0f, x0 = (int)x0f;
      int vy0 = (y0>=0)&&(y0<Hh), vy1 = (y0+1>=0)&&(y0+1<Hh);
      int vx0 = (x0>=0)&&(x0<Ww), vx1 = (x0+1>=0)&&(x0+1<Ww);
      int yc0 = min(max(y0,0),Hh-1),  yc1 = min(max(y0+1,0),Hh-1);
      int xc0 = min(max(x0,0),Ww-1),  xc1 = min(max(x0+1,0),Ww-1);
      float w00 = (1.f-wy)*(1.f-wx)*(float)(vy0&vx0);
      float w01 = (1.f-wy)*wx      *(float)(vy0&vx1);
      float w10 = wy*(1.f-wx)      *(float)(vy1&vx0);
      float w11 = wy*wx            *(float)(vy1&vx1);
      size_t i00 = (size_t)yc0*Ww+xc0, i01 = (size_t)yc0*Ww+xc1;
      size_t i10 = (size_t)yc1*Ww+xc0, i11 = (size_t)yc1*Ww+xc1;
      const float* sgb = supp + ((size_t)b*64 + dg*8)*HWn;
      #pragma unroll
      for (int cg=0;cg<8;++cg){
        const float* p = sgb + (size_t)cg*HWn;
        float v = w00*p[i00] + w01*p[i01] + w10*p[i10] + w11*p[i11];
        s_g[cg*256 + sp] = v * m;
      }
      __syncthreads();
      #pragma unroll
      for (int cg=0;cg<8;++cg){
        const float4* ab = (const float4*)&s_g[cg*256 + r*16 + cc];
        float4 a0 = ab[0], a1 = ab[1];
        float av[8] = {a0.x,a0.y,a0.z,a0.w,a1.x,a1.y,a1.z,a1.w};
        const float4* wb = (const float4*)&w_k[(dg*8+cg)*64 + og*8];
        float4 w0 = wb[0], w1 = wb[1];
        float wv[8] = {w0.x,w0.y,w0.z,w0.w,w1.x,w1.y,w1.z,w1.w};
        #pragma unroll
        for (int o=0;o<8;++o)
          #pragma unroll
          for (int j=0;j<8;++j)
            acc[j][o] = fmaf(av[j], wv[o], acc[j][o]);
      }
    }
  }
  #pragma unroll
  for (int o=0;o<8;++o){
    size_t base = ((size_t)(b*64 + og*8 + o))*HWn + (size_t)(tileY + r)*Ww + tileX + cc;
    float4 s0 = {acc[0][o],acc[1][o],acc[2][o],acc[3][o]};
    float4 s1 = {acc[4][o],acc[5][o],acc[6][o],acc[7][o]};
    *(float4*)(out+base)   = s0;
    *(float4*)(out+base+4) = s1;
  }
}

// ===========================================================================
// FALLBACK PATH (round-5/6 passing VALU pipeline, used when ws < 64 MiB)
// ===========================================================================
__global__ __launch_bounds__(256)
void warp_k(const float* __restrict__ supp, const float* __restrict__ flow,
            float* __restrict__ out)
{
  int pix = blockIdx.x*256 + threadIdx.x;
  int b   = blockIdx.y;
  int py = pix >> 8, px = pix & 255;
  float fx = flow[((size_t)b*2+0)*HWn + pix];
  float fy = flow[((size_t)b*2+1)*HWn + pix];
  float sy = (float)py + fy, sx = (float)px + fx;
  float y0f = floorf(sy), x0f = floorf(sx);
  float wy = sy - y0f,   wx = sx - x0f;
  int y0 = (int)y0f, x0 = (int)x0f;
  int vy0 = (y0>=0)&&(y0<Hh), vy1 = (y0+1>=0)&&(y0+1<Hh);
  int vx0 = (x0>=0)&&(x0<Ww), vx1 = (x0+1>=0)&&(x0+1<Ww);
  int yc0 = min(max(y0,0),Hh-1),  yc1 = min(max(y0+1,0),Hh-1);
  int xc0 = min(max(x0,0),Ww-1),  xc1 = min(max(x0+1,0),Ww-1);
  float w00 = (1.f-wy)*(1.f-wx)*(float)(vy0&vx0);
  float w01 = (1.f-wy)*wx      *(float)(vy0&vx1);
  float w10 = wy*(1.f-wx)      *(float)(vy1&vx0);
  float w11 = wy*wx            *(float)(vy1&vx1);
  size_t i00 = (size_t)yc0*Ww+xc0, i01 = (size_t)yc0*Ww+xc1;
  size_t i10 = (size_t)yc1*Ww+xc0, i11 = (size_t)yc1*Ww+xc1;
  const float* sb = supp + (size_t)b*64*HWn;
  #pragma unroll 4
  for (int c=0;c<64;++c){
    const float* p = sb + (size_t)c*HWn;
    float v = w00*p[i00] + w01*p[i01] + w10*p[i10] + w11*p[i11];
    out[((size_t)b*64+c)*HWn + pix] = v;
  }
}

template<int D, int CIN, bool OUTH>
__global__ __launch_bounds__(256,2)
void conv3x3_k(const float* __restrict__ in0, const float* __restrict__ in1,
               const float* __restrict__ wgt, const float* __restrict__ bias,
               const float* __restrict__ addsrc, float addscale,
               float* __restrict__ out, __half* __restrict__ outh,
               int coutTotal, int actMode)
{
  constexpr int COUTB = 64;
  constexpr int ROWS = 16 + 2*D;
  constexpr int WT   = 16 + 2*D;
  constexpr int WS   = (WT + 3) & ~3;
  constexpr int TT   = ROWS*WS;
  constexpr int NCHUNK = CIN/8;
  __shared__ float in_t[8*TT];
  __shared__ float w_t[72*COUTB];

  const int tid = threadIdx.x;
  const int og  = tid & 7;
  const int pg  = tid >> 3;
  const int r   = pg >> 1;
  const int cc  = (pg & 1)*8;
  const int tileY = (blockIdx.x >> 4)*16, tileX = (blockIdx.x & 15)*16;
  const int b = blockIdx.y;
  const int coutBase = blockIdx.z*COUTB;

  float acc[8][8];
  {
    float bv[8];
    #pragma unroll
    for (int o=0;o<8;++o){
      int co = coutBase + og*8 + o;
      bv[o] = (co < coutTotal) ? bias[co] : 0.f;
    }
    #pragma unroll
    for (int j=0;j<8;++j)
      #pragma unroll
      for (int o=0;o<8;++o) acc[j][o] = bv[o];
  }

  for (int chk=0; chk<NCHUNK; ++chk){
    __syncthreads();
    const int cinBase = chk*8;
    for (int idx=tid; idx < 8*ROWS*WT; idx += 256){
      int c   = idx / (ROWS*WT);
      int rem = idx - c*(ROWS*WT);
      int rr  = rem / WT;
      int xx  = rem - rr*WT;
      int gy = tileY - D + rr, gx = tileX - D + xx;
      int cg = cinBase + c;
      float v = 0.f;
      if (gy>=0 && gy<Hh && gx>=0 && gx<Ww){
        const float* src; int cl;
        if (CIN==128){ if (cg<64){ src=in0; cl=cg; } else { src=in1; cl=cg-64; } }
        else         { src=in0; cl=cg; }
        v = src[((size_t)b*64 + cl)*HWn + (size_t)gy*Ww + gx];
      }
      in_t[c*TT + rr*WS + xx] = v;
    }
    for (int idx=tid; idx < 72*COUTB; idx += 256){
      int oo = idx / 72;
      int rr = idx - oo*72;
      float wv = 0.f;
      if (coutBase + oo < coutTotal)
        wv = wgt[((size_t)(coutBase+oo)*CIN + cinBase)*9 + rr];
      w_t[rr*COUTB + oo] = wv;
    }
    __syncthreads();
    #pragma unroll
    for (int c=0;c<8;++c){
      #pragma unroll
      for (int ki=0;ki<3;++ki){
        constexpr int NR = (D==4)?16:12;
        float row[NR];
        const float4* rbp = (const float4*)&in_t[c*TT + (r + ki*D)*WS + cc];
        #pragma unroll
        for (int q=0;q<NR/4;++q){
          float4 tq = rbp[q];
          row[4*q+0]=tq.x; row[4*q+1]=tq.y; row[4*q+2]=tq.z; row[4*q+3]=tq.w;
        }
        #pragma unroll
        for (int kj=0;kj<3;++kj){
          const float4* wb = (const float4*)&w_t[(c*9 + ki*3 + kj)*COUTB + og*8];
          float4 w0 = wb[0], w1 = wb[1];
          float wv[8] = {w0.x,w0.y,w0.z,w0.w,w1.x,w1.y,w1.z,w1.w};
          #pragma unroll
          for (int o=0;o<8;++o)
            #pragma unroll
            for (int j=0;j<8;++j)
              acc[j][o] = fmaf(row[kj*D + j], wv[o], acc[j][o]);
        }
      }
    }
  }
  #pragma unroll
  for (int o=0;o<8;++o){
    int co = coutBase + og*8 + o;
    if (co >= coutTotal) continue;
    size_t base = ((size_t)(b*coutTotal + co))*HWn
                + (size_t)(tileY + r)*Ww + tileX + cc;
    float v[8];
    #pragma unroll
    for (int j=0;j<8;++j) v[j] = act_apply(acc[j][o], actMode);
    if (addsrc){
      #pragma unroll
      for (int j=0;j<8;++j) v[j] = addsrc[base+j] + addscale*v[j];
    }
    if (!OUTH){
      float4 s0 = {v[0],v[1],v[2],v[3]}, s1 = {v[4],v[5],v[6],v[7]};
      *(float4*)(out+base)   = s0;
      *(float4*)(out+base+4) = s1;
    } else {
      union { __half h[8]; float4 f4; } u;
      #pragma unroll
      for (int j=0;j<8;++j) u.h[j] = __float2half(v[j]);
      *(float4*)(outh+base) = u.f4;
    }
  }
}

// ===========================================================================
extern "C" void kernel_launch(void* const* d_in, const int* in_sizes, int n_in,
                              void* d_out, int out_size, void* d_ws, size_t ws_size,
                              hipStream_t stream)
{
  const float* ref  = (const float*)d_in[0];
  const float* supp = (const float*)d_in[1];
  const float* flow = (const float*)d_in[2];
  const float* fc_w = (const float*)d_in[3];
  const float* fc_b = (const float*)d_in[4];
  const float* c1_w = (const float*)d_in[5];
  const float* c1_b = (const float*)d_in[6];
  const float* c2_w = (const float*)d_in[7];
  const float* c2_b = (const float*)d_in[8];
  const float* c3_w = (const float*)d_in[9];
  const float* c3_b = (const float*)d_in[10];
  const float* c4_w = (const float*)d_in[11];
  const float* c4_b = (const float*)d_in[12];
  const float* c5_w = (const float*)d_in[13];
  const float* c5_b = (const float*)d_in[14];
  const float* c6_w = (const float*)d_in[15];
  const float* c6_b = (const float*)d_in[16];
  const float* off_w= (const float*)d_in[17];
  const float* off_b= (const float*)d_in[18];
  const float* dcn_w= (const float*)d_in[19];
  const float* dcn_b= (const float*)d_in[20];

  // MFMA path needs 64*nb MiB of ws. wprep lives in the d_out tail (2.6MB),
  // which is only overwritten by the final dcn dispatch (after last read).
  const size_t MiB64 = 67108864ull;
  int nb = (ws_size >= 4*MiB64) ? 4 : (ws_size >= 2*MiB64) ? 2 :
           (ws_size >= MiB64)   ? 1 : 0;

  if (nb > 0){
    // ---- weight prep (sets: fc, c1..c6, off) ----
    const size_t FCW = 221184, REGW = 110592;
    u16* wpAll = (u16*)((char*)d_out + (size_t)out_size*4 - 2*(FCW + 6*REGW + 442368));
    u16* wpFC = wpAll;
    u16* wpC1 = wpFC + FCW;
    u16* wpC2 = wpC1 + REGW;
    u16* wpC3 = wpC2 + REGW;
    u16* wpC4 = wpC3 + REGW;
    u16* wpC5 = wpC4 + REGW;
    u16* wpC6 = wpC5 + REGW;
    u16* wpOF = wpC6 + REGW;
    wprep_k<<<dim3(864),256,0,stream>>>(fc_w, wpFC, 128, 12, 4, 64);
    wprep_k<<<dim3(432),256,0,stream>>>(c1_w, wpC1, 64, 6, 4, 64);
    wprep_k<<<dim3(432),256,0,stream>>>(c2_w, wpC2, 64, 6, 4, 64);
    wprep_k<<<dim3(432),256,0,stream>>>(c3_w, wpC3, 64, 6, 4, 64);
    wprep_k<<<dim3(432),256,0,stream>>>(c4_w, wpC4, 64, 6, 4, 64);
    wprep_k<<<dim3(432),256,0,stream>>>(c5_w, wpC5, 64, 6, 4, 64);
    wprep_k<<<dim3(432),256,0,stream>>>(c6_w, wpC6, 64, 6, 4, 64);
    wprep_k<<<dim3(1728),256,0,stream>>>(off_w, wpOF, 64, 6, 16, 216);

    // ws layout per chain (bytes): W[0,16nb MiB) -> t1 overlay; R; F; ACC.
    // o216h (fp16 NCHW, 27nb MiB) overlays [0, ...): W/t1 and R dead by then.
    size_t TEN = (size_t)nb * 16777216ull;
    char* wsb = (char*)d_ws;
    u16* W  = (u16*)(wsb);
    u16* Rf = (u16*)(wsb + TEN);
    u16* F  = (u16*)(wsb + 2*TEN);
    u16* AC = (u16*)(wsb + 3*TEN);
    u16* T1 = W;
    __half* o216h = (__half*)wsb;

    for (int b0 = 0; b0 < Bn; b0 += nb){
      const float* suppb = supp + (size_t)b0*64*HWn;
      const float* refb  = ref  + (size_t)b0*64*HWn;
      const float* flowb = flow + (size_t)b0*2*HWn;
      float* outb = (float*)d_out + (size_t)b0*64*HWn;
      dim3 g(256, nb, 1), g4(256, nb, 4), gd(256, nb);

      warpcvt_k<<<g,256,0,stream>>>(suppb, flowb, W);
      refcvt_k <<<g,256,0,stream>>>(refb, Rf);
      mconv_k<1,12,true ,0><<<g ,256,0,stream>>>(W, Rf, wpFC, 4, fc_b, nullptr, 0.f, F, nullptr, 64, ACT_LRELU);
      mconv_k<1, 6,false,0><<<g ,256,0,stream>>>(F, nullptr, wpC1, 4, c1_b, nullptr, 0.f, T1, nullptr, 64, ACT_RELU);
      mconv_k<1, 6,false,0><<<g ,256,0,stream>>>(T1, nullptr, wpC2, 4, c2_b, F, 1.0f, AC, nullptr, 64, ACT_RELU);
      mconv_k<2, 6,false,0><<<g ,256,0,stream>>>(F, nullptr, wpC3, 4, c3_b, nullptr, 0.f, T1, nullptr, 64, ACT_RELU);
      mconv_k<2, 6,false,0><<<g ,256,0,stream>>>(T1, nullptr, wpC4, 4, c4_b, AC, 0.1f, AC, nullptr, 64, ACT_RELU);
      mconv_k<2, 6,false,0><<<g ,256,0,stream>>>(F, nullptr, wpC5, 4, c5_b, nullptr, 0.f, T1, nullptr, 64, ACT_RELU);
      mconv_k<4, 6,false,0><<<g ,256,0,stream>>>(T1, nullptr, wpC6, 4, c6_b, AC, 0.1f, AC, nullptr, 64, ACT_RELU);
      mconv_k<1, 6,false,2><<<g4,256,0,stream>>>(AC, nullptr, wpOF, 16, off_b, nullptr, 0.f, nullptr, o216h, 216, ACT_NONE);
      dcn_k<<<gd,256,0,stream>>>(suppb, flowb, o216h, dcn_w, dcn_b, outb);
    }
    return;
  }

  // ---- VALU fallback (round-5 pipeline; ws needs 32*nbo MB) ----
  int nbo = (ws_size >= (size_t)Bn*33554432) ? Bn
          : (ws_size >= (size_t)2*33554432) ? 2 : 1;
  float* ws = (float*)d_ws;
  for (int b0 = 0; b0 < Bn; b0 += nbo){
    const float* refb  = ref  + (size_t)b0*64*HWn;
    const float* suppb = supp + (size_t)b0*64*HWn;
    const float* flowb = flow + (size_t)b0*2*HWn;
    float*  outb  = (float*)d_out + (size_t)b0*64*HWn;
    float*  warpb = ws;
    float*  t1    = ws;
    float*  feat0 = ws + (size_t)nbo*4194304;
    __half* o216h = (__half*)d_ws;
    float*  accb  = outb;

    dim3 cgrid(256, nbo, 1);
    warp_k<<<dim3(256,nbo),256,0,stream>>>(suppb, flowb, warpb);
    conv3x3_k<1,128,false><<<cgrid,256,0,stream>>>(warpb, refb,    fc_w, fc_b, nullptr, 0.f,  feat0, nullptr, 64, ACT_LRELU);
    conv3x3_k<1, 64,false><<<cgrid,256,0,stream>>>(feat0, nullptr, c1_w, c1_b, nullptr, 0.f,  t1,    nullptr, 64, ACT_RELU);
    conv3x3_k<1, 64,false><<<cgrid,256,0,stream>>>(t1,    nullptr, c2_w, c2_b, feat0,  1.0f,  accb,  nullptr, 64, ACT_RELU);
    conv3x3_k<2, 64,false><<<cgrid,256,0,stream>>>(feat0, nullptr, c3_w, c3_b, nullptr, 0.f,  t1,    nullptr, 64, ACT_RELU);
    conv3x3_k<2, 64,false><<<cgrid,256,0,stream>>>(t1,    nullptr, c4_w, c4_b, accb,   0.1f,  accb,  nullptr, 64, ACT_RELU);
    conv3x3_k<2, 64,false><<<cgrid,256,0,stream>>>(feat0, nullptr, c5_w, c5_b, nullptr, 0.f,  t1,    nullptr, 64, ACT_RELU);
    conv3x3_k<4, 64,false><<<cgrid,256,0,stream>>>(t1,    nullptr, c6_w, c6_b, accb,   0.1f,  accb,  nullptr, 64, ACT_RELU);
    conv3x3_k<1, 64,true ><<<dim3(256,nbo,4),256,0,stream>>>(accb, nullptr, off_w, off_b, nullptr, 0.f, nullptr, o216h, 216, ACT_NONE);
    dcn_k<<<dim3(256,nbo),256,0,stream>>>(suppb, flowb, o216h, dcn_w, dcn_b, outb);
  }
}